// Round 11
// baseline (440.556 us; speedup 1.0000x reference)
//
#include <hip/hip_runtime.h>

// BertEmbedding + 5-layer GAT on MI355X (gfx950). Round 16:
//  - Round-15 post-mortem: GEMM "L2 capacity" theory was arithmetically
//    wrong (per-layer B = 2.56 MB, not 12.8 -> already L2-resident); the
//    super-tile+swizzle bundle measured +5.6us (neutral/negative). GEMM
//    reverted to round-14 exact mapping. Front keeps round-15 vectorized
//    loads (audited, low-risk).
//  - This round's one structural change: k_gat_last DELETED. k_final's 64
//    CLS rows compute their own layer-4 GAT inline from C + CSR (12
//    features/lane, hidden under the 59us stream: only 64/16384 waves).
//    Saves a dispatch + drain + the xf HBM round-trip. 12 -> 11 dispatches.
//  - Budget: ~180us fills (fixed) + final ~59 (capped, accepted) + gemm ~45
//    + gat ~28 + front ~30. If this round lands >=364, structural floor.

#define DEV __device__ __forceinline__

typedef short s16x8 __attribute__((ext_vector_type(8)));
typedef float f32x4 __attribute__((ext_vector_type(4)));
typedef unsigned short u16x8 __attribute__((ext_vector_type(8)));

DEV float b2f(unsigned int u) { union { unsigned int i; float f; } v; v.i = u << 16; return v.f; }
DEV unsigned short f2b(float f) {
  union { float f; unsigned int i; } v; v.f = f;
  return (unsigned short)((v.i + 0x7fffu + ((v.i >> 16) & 1u)) >> 16);
}
DEV float gelu_exact(float x) { return 0.5f * x * (1.f + erff(x * 0.70710678118654752f)); }

// dual-dtype loads. fF: floats are f32 (else bf16). fI: ints are int64.
DEV float ldf(const void* p, size_t i, int fF) {
  return fF ? ((const float*)p)[i] : b2f(((const unsigned short*)p)[i]);
}
DEV int ldi(const void* p, size_t i, int fI) {
  return fI ? ((const int*)p)[2 * i] : ((const int*)p)[i];
}

// Fragment-linear offset for element [n][d] of a [rows][768] matrix.
DEV size_t frag_off(int n, int d) {
  return ((((size_t)(n >> 4) * 24 + (size_t)(d >> 5)) * 64 +
           (((d >> 3) & 3) << 4) + (n & 15)) << 3) + (d & 7);
}

// ---------------------------------------------------------------------------
// k_front: fused front-end, 1357 blocks (round-15 version: f32x4 Wg loads on
// the fF path, span src-index prefetch; otherwise round-9 exact).
// ---------------------------------------------------------------------------
__global__ __launch_bounds__(256) void k_front(const void* __restrict__ src,
                                               const void* __restrict__ sst,
                                               const void* __restrict__ sen,
                                               const void* __restrict__ edge,
                                               const void* __restrict__ word,
                                               const void* __restrict__ pos,
                                               const void* __restrict__ aS,
                                               const void* __restrict__ aD,
                                               const void* __restrict__ Wg,
                                               unsigned short* __restrict__ xh,
                                               unsigned short* __restrict__ xl,
                                               unsigned short* __restrict__ Bh,
                                               unsigned short* __restrict__ Bl,
                                               int* __restrict__ csr_off,
                                               int* __restrict__ csr_src,
                                               int* __restrict__ flags) {
  __shared__ int sflags[2];
  __shared__ float tile[64][65];
  __shared__ float sA[768], sD[768];
  __shared__ int cnt[576], off[577], fill[576];
  int t = threadIdx.x, bid = blockIdx.x;
  if (t < 64) {
    const unsigned short* w16 = (const unsigned short*)word;
    int crazy = 0;
    for (int i = t; i < 512; i += 64) {
      unsigned int e = (w16[i] >> 7) & 0xffu;
      if (e >= 135u || (e >= 1u && e <= 100u)) crazy++;
    }
#pragma unroll
    for (int o = 32; o > 0; o >>= 1) crazy += __shfl_down(crazy, o);
    if (t == 0) {
      sflags[0] = (crazy >= 8) ? 1 : 0;
      sflags[1] = (((const int*)pos)[1] == 0) ? 1 : 0;
    }
  }
  __syncthreads();
  int fF = sflags[0], fI = sflags[1];
  if (bid == 0 && t == 0) { flags[0] = fF; flags[1] = fI; }

  if (bid < 780) {
    int layer = bid / 156, r = bid % 156, kt = r / 13, nt = r % 13;
    int k0 = kt * 64, n0 = nt * 64;
    if (nt < 12) {
      if (fF) {
        const float* Wf = (const float*)Wg;
#pragma unroll
        for (int i = 0; i < 4; ++i) {
          int e = t + 256 * i, rk = e >> 4, c4 = (e & 15) * 4;
          f32x4 v = *(const f32x4*)(Wf + ((size_t)layer * 768 + k0 + rk) * 768 + n0 + c4);
          tile[rk][c4] = v[0]; tile[rk][c4 + 1] = v[1];
          tile[rk][c4 + 2] = v[2]; tile[rk][c4 + 3] = v[3];
        }
      } else {
#pragma unroll
        for (int i = 0; i < 16; ++i) {
          int e = t + 256 * i, rk = e >> 6, cn = e & 63;
          tile[rk][cn] = ldf(Wg, ((size_t)layer * 768 + k0 + rk) * 768 + n0 + cn, fF);
        }
      }
    } else {
      for (int i = t; i < 768; i += 256) {
        sA[i] = ldf(aS, (size_t)layer * 768 + i, fF);
        sD[i] = ldf(aD, (size_t)layer * 768 + i, fF);
      }
#pragma unroll
      for (int i = 0; i < 16; ++i) {
        int e = t + 256 * i, rk = e >> 6, cn = e & 63;
        if (cn >= 8) tile[rk][cn] = 0.f;
      }
      __syncthreads();
      int wave = t >> 6, lane = t & 63;
      for (int rr = 0; rr < 16; ++rr) {
        int rk = wave * 16 + rr;
        size_t wbase = ((size_t)layer * 768 + k0 + rk) * 768;
        float accS[4] = {0.f, 0.f, 0.f, 0.f}, accD[4] = {0.f, 0.f, 0.f, 0.f};
#pragma unroll
        for (int i = 0; i < 12; ++i) {
          int d = lane + 64 * i;
          float w = ldf(Wg, wbase + d, fF);
          accS[i / 3] += w * sA[d];
          accD[i / 3] += w * sD[d];
        }
#pragma unroll
        for (int h = 0; h < 4; ++h) {
          float sS = accS[h], sDv = accD[h];
#pragma unroll
          for (int o = 32; o > 0; o >>= 1) {
            sS += __shfl_down(sS, o);
            sDv += __shfl_down(sDv, o);
          }
          if (lane == 0) { tile[rk][h] = sS; tile[rk][4 + h] = sDv; }
        }
      }
    }
    __syncthreads();
    size_t lb = (size_t)layer * 79872;
#pragma unroll
    for (int g = 0; g < 2; ++g) {
      int G = t * 2 + g, rn = G & 63, c8 = G >> 6;
      int n = n0 + rn, kb = k0 + c8 * 8;
      u16x8 hv, lv;
#pragma unroll
      for (int j = 0; j < 8; ++j) {
        float v = tile[c8 * 8 + j][rn];
        unsigned short hi = f2b(v);
        hv[j] = hi;
        lv[j] = f2b(v - b2f((unsigned int)hi));
      }
      size_t go = lb + ((size_t)(n >> 4) * 24 + (size_t)(kb >> 5)) * 64 +
                  (((kb >> 3) & 3) << 4) + (n & 15);
      *(u16x8*)(Bh + go * 8) = hv;
      *(u16x8*)(Bl + go * 8) = lv;
    }
  } else if (bid < 1356) {
    int g = bid - 780;
    int b = g / 9, j = g % 9;
    float v[3] = {0.f, 0.f, 0.f};
    if (j == 0) {
      int rr = ldi(src, (size_t)b * 512, fI);
#pragma unroll
      for (int ii = 0; ii < 3; ++ii) v[ii] = ldf(word, (size_t)rr * 768 + t + 256 * ii, fF);
    } else {
      int st = ldi(sst, (size_t)b * 8 + j - 1, fI);
      int en = ldi(sen, (size_t)b * 8 + j - 1, fI);
      int cntr = en - st + 1;  // in [2,8] (span_len in [1,8), inclusive end)
      int rows[8];
#pragma unroll 8
      for (int q = 0; q < 8; ++q)
        if (q < cntr) rows[q] = ldi(src, (size_t)b * 512 + st + q, fI);
      for (int q = 0; q < cntr; ++q) {
        int rr = rows[q];
#pragma unroll
        for (int ii = 0; ii < 3; ++ii) v[ii] += ldf(word, (size_t)rr * 768 + t + 256 * ii, fF);
      }
    }
#pragma unroll
    for (int ii = 0; ii < 3; ++ii) {
      int d = t + 256 * ii;
      unsigned short hi = f2b(v[ii]);
      size_t o = frag_off(g, d);
      xh[o] = hi;
      xl[o] = f2b(v[ii] - b2f((unsigned int)hi));
    }
  } else {
    for (int i = t; i < 576; i += 256) cnt[i] = 0;
    __syncthreads();
    for (int e = t; e < 8768; e += 256) {
      int di;
      if (e < 4096) di = ldi(edge, (size_t)4096 + e, fI);
      else if (e < 8192) di = ldi(edge, (size_t)e - 4096, fI);
      else di = e - 8192;
      atomicAdd(&cnt[di], 1);
    }
    __syncthreads();
    if (t == 0) {
      int a = 0;
      for (int i = 0; i < 576; ++i) { off[i] = a; a += cnt[i]; }
      off[576] = a;
    }
    __syncthreads();
    for (int i = t; i < 577; i += 256) csr_off[i] = off[i];
    for (int i = t; i < 576; i += 256) fill[i] = off[i];
    __syncthreads();
    for (int e = t; e < 8768; e += 256) {
      int si, di;
      if (e < 4096)      { si = ldi(edge, (size_t)e, fI); di = ldi(edge, (size_t)4096 + e, fI); }
      else if (e < 8192) { si = ldi(edge, (size_t)e, fI); di = ldi(edge, (size_t)e - 4096, fI); }
      else               { si = e - 8192;                 di = si; }
      int p = atomicAdd(&fill[di], 1);
      csr_src[p] = si;
    }
  }
}

// ---------------------------------------------------------------------------
// k_gemm: round-14 exact. 468 blocks x 4 waves, one 16x16 C-tile per wave,
// LDS-free, barrier-free, 3 MFMA chains. (Round-15 super-tile/XCD-swizzle
// measured neutral-negative -> reverted.)
// ---------------------------------------------------------------------------
__global__ __launch_bounds__(256) void k_gemm(const unsigned short* __restrict__ xh,
                                              const unsigned short* __restrict__ xl,
                                              const unsigned short* __restrict__ Bh,
                                              const unsigned short* __restrict__ Bl,
                                              float* __restrict__ C) {
  int t = threadIdx.x;
  int wid = blockIdx.x * 4 + (t >> 6), lane = t & 63;
  int rt = wid / 52, ct = wid % 52;
  const s16x8* Ah = (const s16x8*)xh + (size_t)rt * 1536 + lane;
  const s16x8* Al = (const s16x8*)xl + (size_t)rt * 1536 + lane;
  const s16x8* Bhp = (const s16x8*)Bh + (size_t)ct * 1536 + lane;
  const s16x8* Blp = (const s16x8*)Bl + (size_t)ct * 1536 + lane;
  f32x4 a0 = {0.f, 0.f, 0.f, 0.f}, a1 = a0, a2 = a0;
#pragma unroll 6
  for (int kk = 0; kk < 24; ++kk) {
    s16x8 ah = Ah[kk * 64];
    s16x8 al = Al[kk * 64];
    s16x8 bh = Bhp[kk * 64];
    s16x8 bl = Blp[kk * 64];
    a0 = __builtin_amdgcn_mfma_f32_16x16x32_bf16(ah, bh, a0, 0, 0, 0);
    a1 = __builtin_amdgcn_mfma_f32_16x16x32_bf16(ah, bl, a1, 0, 0, 0);
    a2 = __builtin_amdgcn_mfma_f32_16x16x32_bf16(al, bh, a2, 0, 0, 0);
  }
  int row0 = rt * 16 + (lane >> 4) * 4, col = ct * 16 + (lane & 15);
#pragma unroll
  for (int r = 0; r < 4; ++r)
    C[(size_t)(row0 + r) * 832 + col] = a0[r] + a1[r] + a2[r];
}

// ---------------------------------------------------------------------------
// GAT aggregate (round-14 verified): 4-deep load batching, bit-identical
// accumulation order.
// ---------------------------------------------------------------------------
DEV float gat_aggregate(const float* __restrict__ C, const int* __restrict__ off,
                        const int* __restrict__ srcs, int n, int d, int h) {
  float aDv = C[(size_t)n * 832 + 772 + h];
  int e0 = off[n], e1 = off[n + 1];
  float num = 0.f, den = 0.f;
  for (int e = e0; e < e1; e += 4) {
    float lg[4], ms[4];
#pragma unroll
    for (int j = 0; j < 4; ++j) {
      int ee = (e + j < e1) ? (e + j) : e0;
      int s = srcs[ee];
      lg[j] = C[(size_t)s * 832 + 768 + h];
      ms[j] = C[(size_t)s * 832 + d];
    }
#pragma unroll
    for (int j = 0; j < 4; ++j) {
      if (e + j < e1) {
        float l = lg[j] + aDv;
        float lrel = l < 0.f ? 0.2f * l : l;
        lrel = fminf(fmaxf(lrel, -60.f), 40.f);
        float w = __expf(lrel);
        num += w * ms[j];
        den += w;
      }
    }
  }
  return num / den;
}

// k_gat (layers 0..3): writes ONLY xh/xl.
__global__ __launch_bounds__(256) void k_gat(const float* __restrict__ C,
                                             const int* __restrict__ off,
                                             const int* __restrict__ srcs,
                                             const void* __restrict__ bG,
                                             const int* __restrict__ flg,
                                             int layer,
                                             unsigned short* __restrict__ xh,
                                             unsigned short* __restrict__ xl) {
  int fF = flg[0];
  int idx = blockIdx.x * 256 + threadIdx.x;  // 576*768
  int n = idx / 768, d = idx - n * 768, h = d / 192;
  float g = gelu_exact(gat_aggregate(C, off, srcs, n, d, h) +
                       ldf(bG, (size_t)layer * 768 + d, fF));
  unsigned short hi = f2b(g);
  size_t o = frag_off(n, d);
  xh[o] = hi;
  xl[o] = f2b(g - b2f((unsigned int)hi));
}

// ---------------------------------------------------------------------------
// k_final: emb = (CLS? gnn_x : word[src]) + pos + seg + type; LayerNorm.
// CLS rows (64 of 32768) compute their own layer-4 GAT inline from C + CSR
// (replaces the k_gat_last dispatch + xf round-trip). Only 64/16384 waves
// take the slow path -> fully hidden under the 59us stream.
// ---------------------------------------------------------------------------
DEV void final_row_f32(int r, int lane, const f32x4* wsrc,
                       const void* seg, const void* typ, const void* post,
                       const void* segt, const void* typt,
                       const void* gamma, const void* beta, int fI,
                       float* __restrict__ outp) {
  int s = r & 511;
  int sg = ldi(seg, (size_t)r, fI), tp = ldi(typ, (size_t)r, fI);
  const f32x4* pr = (const f32x4*)((const float*)post + (size_t)s * 768);
  const f32x4* sr = (const f32x4*)((const float*)segt + (size_t)sg * 768);
  const f32x4* tr = (const f32x4*)((const float*)typt + (size_t)tp * 768);
  float sum = 0.f, sq = 0.f;
  f32x4 vv[3];
#pragma unroll
  for (int j = 0; j < 3; ++j) {
    int p = lane + 64 * j;
    f32x4 a = wsrc[j];
    a += pr[p]; a += sr[p]; a += tr[p];
    vv[j] = a;
#pragma unroll
    for (int c = 0; c < 4; ++c) { sum += a[c]; sq += a[c] * a[c]; }
  }
#pragma unroll
  for (int o = 32; o > 0; o >>= 1) { sum += __shfl_down(sum, o); sq += __shfl_down(sq, o); }
  sum = __shfl(sum, 0); sq = __shfl(sq, 0);
  float mu = sum * (1.f / 768.f);
  float var = fmaxf(sq * (1.f / 768.f) - mu * mu, 0.f);
  float rstd = rsqrtf(var + 1e-6f);
  const f32x4* gm = (const f32x4*)gamma;
  const f32x4* bt = (const f32x4*)beta;
  f32x4* orow = (f32x4*)(outp + (size_t)r * 768);
#pragma unroll
  for (int j = 0; j < 3; ++j) {
    int p = lane + 64 * j;
    f32x4 g4 = gm[p], b4 = bt[p], y;
#pragma unroll
    for (int c = 0; c < 4; ++c) y[c] = g4[c] * (vv[j][c] - mu) * rstd + b4[c];
    __builtin_nontemporal_store(y, &orow[p]);
  }
}

DEV void final_row_bf16(int r, int lane, const void* src, const void* seg,
                        const void* typ, const void* word, const void* post,
                        const void* segt, const void* typt, const void* gamma,
                        const void* beta, const float* __restrict__ C,
                        const int* __restrict__ off, const int* __restrict__ srcs,
                        const void* bG, int fI,
                        unsigned short* __restrict__ outp) {
  int b = r >> 9, s = r & 511;
  int sg = ldi(seg, (size_t)r, fI), tp = ldi(typ, (size_t)r, fI);
  int wrow = ldi(src, (size_t)r, fI);
  bool cls = (s == 0);
  float sum = 0.f, sq = 0.f;
  float vs[12];
#pragma unroll
  for (int j = 0; j < 12; ++j) {
    int d = lane + 64 * j;
    float xv;
    if (cls) {
      xv = gelu_exact(gat_aggregate(C, off, srcs, b * 9, d, d / 192) +
                      ldf(bG, (size_t)4 * 768 + d, 0));
    } else {
      xv = ldf(word, (size_t)wrow * 768 + d, 0);
    }
    xv += ldf(post, (size_t)s * 768 + d, 0);
    xv += ldf(segt, (size_t)sg * 768 + d, 0);
    xv += ldf(typt, (size_t)tp * 768 + d, 0);
    vs[j] = xv;
    sum += xv; sq += xv * xv;
  }
#pragma unroll
  for (int o = 32; o > 0; o >>= 1) { sum += __shfl_down(sum, o); sq += __shfl_down(sq, o); }
  sum = __shfl(sum, 0); sq = __shfl(sq, 0);
  float mu = sum * (1.f / 768.f);
  float var = fmaxf(sq * (1.f / 768.f) - mu * mu, 0.f);
  float rstd = rsqrtf(var + 1e-6f);
#pragma unroll
  for (int j = 0; j < 12; ++j) {
    int d = lane + 64 * j;
    float y = ldf(gamma, (size_t)d, 0) * (vs[j] - mu) * rstd + ldf(beta, (size_t)d, 0);
    outp[(size_t)r * 768 + d] = f2b(y);
  }
}

// Fill one CLS row's 12 features (f32x4 x3) via inline layer-4 GAT.
DEV void cls_fill_f32(const float* __restrict__ C, const int* __restrict__ off,
                      const int* __restrict__ srcs, const void* bG, int fF,
                      int b, int lane, f32x4* wa) {
  int n = b * 9;
#pragma unroll
  for (int j = 0; j < 3; ++j) {
#pragma unroll
    for (int c = 0; c < 4; ++c) {
      int d = (lane + 64 * j) * 4 + c;
      wa[j][c] = gelu_exact(gat_aggregate(C, off, srcs, n, d, d / 192) +
                            ldf(bG, (size_t)4 * 768 + d, fF));
    }
  }
}

__global__ __launch_bounds__(256) void k_final(const void* __restrict__ src,
                                               const void* __restrict__ seg,
                                               const void* __restrict__ typ,
                                               const void* __restrict__ word,
                                               const void* __restrict__ post,
                                               const void* __restrict__ segt,
                                               const void* __restrict__ typt,
                                               const void* __restrict__ gamma,
                                               const void* __restrict__ beta,
                                               const float* __restrict__ C,
                                               const int* __restrict__ csr_off,
                                               const int* __restrict__ csr_src,
                                               const void* __restrict__ bG,
                                               const int* __restrict__ flg,
                                               void* __restrict__ out) {
  int fF = flg[0], fI = flg[1];
  int wave = threadIdx.x >> 6, lane = threadIdx.x & 63;
  int r0 = blockIdx.x * 4 + wave, r1 = r0 + 16384;
  if (fF) {
    int s0 = r0 & 511, s1 = r1 & 511;
    int b0 = r0 >> 9, b1 = r1 >> 9;
    int w0r = ldi(src, (size_t)r0, fI), w1r = ldi(src, (size_t)r1, fI);
    f32x4 wa[3], wb[3];
    if (s0 != 0 && s1 != 0) {
      // hot path: hoist both rows' word gathers (2 HBM latency streams)
      const f32x4* p0 = (const f32x4*)((const float*)word + (size_t)w0r * 768);
      const f32x4* p1 = (const f32x4*)((const float*)word + (size_t)w1r * 768);
#pragma unroll
      for (int j = 0; j < 3; ++j) { wa[j] = p0[lane + 64 * j]; wb[j] = p1[lane + 64 * j]; }
    } else {
      if (s0 == 0) cls_fill_f32(C, csr_off, csr_src, bG, fF, b0, lane, wa);
      else {
        const f32x4* p0 = (const f32x4*)((const float*)word + (size_t)w0r * 768);
#pragma unroll
        for (int j = 0; j < 3; ++j) wa[j] = p0[lane + 64 * j];
      }
      if (s1 == 0) cls_fill_f32(C, csr_off, csr_src, bG, fF, b1, lane, wb);
      else {
        const f32x4* p1 = (const f32x4*)((const float*)word + (size_t)w1r * 768);
#pragma unroll
        for (int j = 0; j < 3; ++j) wb[j] = p1[lane + 64 * j];
      }
    }
    final_row_f32(r0, lane, wa, seg, typ, post, segt, typt, gamma, beta, fI, (float*)out);
    final_row_f32(r1, lane, wb, seg, typ, post, segt, typt, gamma, beta, fI, (float*)out);
  } else {
    final_row_bf16(r0, lane, src, seg, typ, word, post, segt, typt, gamma, beta,
                   C, csr_off, csr_src, bG, fI, (unsigned short*)out);
    final_row_bf16(r1, lane, src, seg, typ, word, post, segt, typt, gamma, beta,
                   C, csr_off, csr_src, bG, fI, (unsigned short*)out);
  }
}

extern "C" void kernel_launch(void* const* d_in, const int* in_sizes, int n_in,
                              void* d_out, int out_size, void* d_ws, size_t ws_size,
                              hipStream_t stream) {
  const void* src  = d_in[0];
  const void* seg  = d_in[1];
  const void* typ  = d_in[2];
  const void* pos  = d_in[3];
  const void* sst  = d_in[4];
  const void* sen  = d_in[5];
  const void* edge = d_in[6];
  const void* word = d_in[7];
  const void* post = d_in[8];
  const void* segt = d_in[9];
  const void* typt = d_in[10];
  const void* gamma = d_in[11];
  const void* beta  = d_in[12];
  const void* Wg    = d_in[13];
  const void* aS    = d_in[14];
  const void* aD    = d_in[15];
  const void* bG    = d_in[16];

  char* ws = (char*)d_ws;
  float* C  = (float*)(ws + 1769472);                     //  1,916,928
  unsigned short* xh = (unsigned short*)(ws + 3686400);   //    884,736 (frag-linear)
  unsigned short* xl = (unsigned short*)(ws + 4571136);   //    884,736
  unsigned short* Bh = (unsigned short*)(ws + 5455872);   //  6,389,760 (5 layers, frag-linear)
  unsigned short* Bl = (unsigned short*)(ws + 11845632);  //  6,389,760
  int* csr_off = (int*)(ws + 18358272);                   //      2,320 (pad)
  int* csr_src = (int*)(ws + 18360592);                   //     35,072
  int* flags   = (int*)(ws + 18395664);                   //          8

  k_front<<<dim3(1357), dim3(256), 0, stream>>>(src, sst, sen, edge, word, pos, aS, aD, Wg,
                                                xh, xl, Bh, Bl, csr_off, csr_src, flags);
  for (int l = 0; l < 4; ++l) {
    k_gemm<<<dim3(468), dim3(256), 0, stream>>>(xh, xl,
                                                Bh + (size_t)l * 832 * 768,
                                                Bl + (size_t)l * 832 * 768, C);
    k_gat<<<dim3(1728), dim3(256), 0, stream>>>(C, csr_off, csr_src, bG, flags, l, xh, xl);
  }
  k_gemm<<<dim3(468), dim3(256), 0, stream>>>(xh, xl,
                                              Bh + (size_t)4 * 832 * 768,
                                              Bl + (size_t)4 * 832 * 768, C);
  k_final<<<dim3(4096), dim3(256), 0, stream>>>(src, seg, typ, word, post, segt, typt,
                                                gamma, beta, C, csr_off, csr_src, bG,
                                                flags, d_out);
}

// Round 14
// 364.900 us; speedup vs baseline: 1.2073x; 1.2073x over previous
//
#include <hip/hip_runtime.h>

// BertEmbedding + 5-layer GAT on MI355X (gfx950). Round 17 = round-14 exact
// revert (measured 364.2us, session best). 3rd submit — two prior attempts
// hit GPUAcquisitionTimeout; kernel never ran. No changes.
//  - Round-16 post-mortem: fusing layer-4 GAT into k_final's CLS rows
//    collapsed 49K-thread parallelism into a 64-wave serial-gather tail ->
//    k_final 59->150us, occupancy 62->9% (time-averaged; the tail runs
//    alone ~100us). Lesson: never trade TLP for dispatch count on
//    dependent-gather code. k_gat_last restored.
//  - Round-15 bundle (gemm super-tile/XCD swizzle + front vectorization)
//    measured neutral-negative (+5.6) -> also reverted.
//  - Budget at 364: ~180us fills (fixed, 80-84% HBM peak), final ~59
//    (pattern cap, 7 falsified interventions), gemm ~45, gat ~28,
//    front ~30, gat_last+drains ~12. If this reproduces ~364: roofline.

#define DEV __device__ __forceinline__

typedef short s16x8 __attribute__((ext_vector_type(8)));
typedef float f32x4 __attribute__((ext_vector_type(4)));
typedef unsigned short u16x8 __attribute__((ext_vector_type(8)));

DEV float b2f(unsigned int u) { union { unsigned int i; float f; } v; v.i = u << 16; return v.f; }
DEV unsigned short f2b(float f) {
  union { float f; unsigned int i; } v; v.f = f;
  return (unsigned short)((v.i + 0x7fffu + ((v.i >> 16) & 1u)) >> 16);
}
DEV float gelu_exact(float x) { return 0.5f * x * (1.f + erff(x * 0.70710678118654752f)); }

// dual-dtype loads. fF: floats are f32 (else bf16). fI: ints are int64.
DEV float ldf(const void* p, size_t i, int fF) {
  return fF ? ((const float*)p)[i] : b2f(((const unsigned short*)p)[i]);
}
DEV int ldi(const void* p, size_t i, int fI) {
  return fI ? ((const int*)p)[2 * i] : ((const int*)p)[i];
}

// Fragment-linear offset for element [n][d] of a [rows][768] matrix.
DEV size_t frag_off(int n, int d) {
  return ((((size_t)(n >> 4) * 24 + (size_t)(d >> 5)) * 64 +
           (((d >> 3) & 3) << 4) + (n & 15)) << 3) + (d & 7);
}

// ---------------------------------------------------------------------------
// k_front: fused front-end, 1357 blocks (round-9/14 exact).
// ---------------------------------------------------------------------------
__global__ __launch_bounds__(256) void k_front(const void* __restrict__ src,
                                               const void* __restrict__ sst,
                                               const void* __restrict__ sen,
                                               const void* __restrict__ edge,
                                               const void* __restrict__ word,
                                               const void* __restrict__ pos,
                                               const void* __restrict__ aS,
                                               const void* __restrict__ aD,
                                               const void* __restrict__ Wg,
                                               unsigned short* __restrict__ xh,
                                               unsigned short* __restrict__ xl,
                                               unsigned short* __restrict__ Bh,
                                               unsigned short* __restrict__ Bl,
                                               int* __restrict__ csr_off,
                                               int* __restrict__ csr_src,
                                               int* __restrict__ flags) {
  __shared__ int sflags[2];
  __shared__ float tile[64][65];
  __shared__ float sA[768], sD[768];
  __shared__ int cnt[576], off[577], fill[576];
  int t = threadIdx.x, bid = blockIdx.x;
  if (t < 64) {
    const unsigned short* w16 = (const unsigned short*)word;
    int crazy = 0;
    for (int i = t; i < 512; i += 64) {
      unsigned int e = (w16[i] >> 7) & 0xffu;
      if (e >= 135u || (e >= 1u && e <= 100u)) crazy++;
    }
#pragma unroll
    for (int o = 32; o > 0; o >>= 1) crazy += __shfl_down(crazy, o);
    if (t == 0) {
      sflags[0] = (crazy >= 8) ? 1 : 0;
      sflags[1] = (((const int*)pos)[1] == 0) ? 1 : 0;
    }
  }
  __syncthreads();
  int fF = sflags[0], fI = sflags[1];
  if (bid == 0 && t == 0) { flags[0] = fF; flags[1] = fI; }

  if (bid < 780) {
    int layer = bid / 156, r = bid % 156, kt = r / 13, nt = r % 13;
    int k0 = kt * 64, n0 = nt * 64;
    if (nt < 12) {
#pragma unroll
      for (int i = 0; i < 16; ++i) {
        int e = t + 256 * i, rk = e >> 6, cn = e & 63;
        tile[rk][cn] = ldf(Wg, ((size_t)layer * 768 + k0 + rk) * 768 + n0 + cn, fF);
      }
    } else {
      for (int i = t; i < 768; i += 256) {
        sA[i] = ldf(aS, (size_t)layer * 768 + i, fF);
        sD[i] = ldf(aD, (size_t)layer * 768 + i, fF);
      }
#pragma unroll
      for (int i = 0; i < 16; ++i) {
        int e = t + 256 * i, rk = e >> 6, cn = e & 63;
        if (cn >= 8) tile[rk][cn] = 0.f;
      }
      __syncthreads();
      int wave = t >> 6, lane = t & 63;
      for (int rr = 0; rr < 16; ++rr) {
        int rk = wave * 16 + rr;
        size_t wbase = ((size_t)layer * 768 + k0 + rk) * 768;
        float accS[4] = {0.f, 0.f, 0.f, 0.f}, accD[4] = {0.f, 0.f, 0.f, 0.f};
#pragma unroll
        for (int i = 0; i < 12; ++i) {
          int d = lane + 64 * i;
          float w = ldf(Wg, wbase + d, fF);
          accS[i / 3] += w * sA[d];
          accD[i / 3] += w * sD[d];
        }
#pragma unroll
        for (int h = 0; h < 4; ++h) {
          float sS = accS[h], sDv = accD[h];
#pragma unroll
          for (int o = 32; o > 0; o >>= 1) {
            sS += __shfl_down(sS, o);
            sDv += __shfl_down(sDv, o);
          }
          if (lane == 0) { tile[rk][h] = sS; tile[rk][4 + h] = sDv; }
        }
      }
    }
    __syncthreads();
    size_t lb = (size_t)layer * 79872;
#pragma unroll
    for (int g = 0; g < 2; ++g) {
      int G = t * 2 + g, rn = G & 63, c8 = G >> 6;
      int n = n0 + rn, kb = k0 + c8 * 8;
      u16x8 hv, lv;
#pragma unroll
      for (int j = 0; j < 8; ++j) {
        float v = tile[c8 * 8 + j][rn];
        unsigned short hi = f2b(v);
        hv[j] = hi;
        lv[j] = f2b(v - b2f((unsigned int)hi));
      }
      size_t go = lb + ((size_t)(n >> 4) * 24 + (size_t)(kb >> 5)) * 64 +
                  (((kb >> 3) & 3) << 4) + (n & 15);
      *(u16x8*)(Bh + go * 8) = hv;
      *(u16x8*)(Bl + go * 8) = lv;
    }
  } else if (bid < 1356) {
    int g = bid - 780;
    int b = g / 9, j = g % 9;
    float v[3] = {0.f, 0.f, 0.f};
    if (j == 0) {
      int rr = ldi(src, (size_t)b * 512, fI);
#pragma unroll
      for (int ii = 0; ii < 3; ++ii) v[ii] = ldf(word, (size_t)rr * 768 + t + 256 * ii, fF);
    } else {
      int st = ldi(sst, (size_t)b * 8 + j - 1, fI);
      int en = ldi(sen, (size_t)b * 8 + j - 1, fI);
      for (int s = st; s <= en; ++s) {
        int rr = ldi(src, (size_t)b * 512 + s, fI);
#pragma unroll
        for (int ii = 0; ii < 3; ++ii) v[ii] += ldf(word, (size_t)rr * 768 + t + 256 * ii, fF);
      }
    }
#pragma unroll
    for (int ii = 0; ii < 3; ++ii) {
      int d = t + 256 * ii;
      unsigned short hi = f2b(v[ii]);
      size_t o = frag_off(g, d);
      xh[o] = hi;
      xl[o] = f2b(v[ii] - b2f((unsigned int)hi));
    }
  } else {
    for (int i = t; i < 576; i += 256) cnt[i] = 0;
    __syncthreads();
    for (int e = t; e < 8768; e += 256) {
      int di;
      if (e < 4096) di = ldi(edge, (size_t)4096 + e, fI);
      else if (e < 8192) di = ldi(edge, (size_t)e - 4096, fI);
      else di = e - 8192;
      atomicAdd(&cnt[di], 1);
    }
    __syncthreads();
    if (t == 0) {
      int a = 0;
      for (int i = 0; i < 576; ++i) { off[i] = a; a += cnt[i]; }
      off[576] = a;
    }
    __syncthreads();
    for (int i = t; i < 577; i += 256) csr_off[i] = off[i];
    for (int i = t; i < 576; i += 256) fill[i] = off[i];
    __syncthreads();
    for (int e = t; e < 8768; e += 256) {
      int si, di;
      if (e < 4096)      { si = ldi(edge, (size_t)e, fI); di = ldi(edge, (size_t)4096 + e, fI); }
      else if (e < 8192) { si = ldi(edge, (size_t)e, fI); di = ldi(edge, (size_t)e - 4096, fI); }
      else               { si = e - 8192;                 di = si; }
      int p = atomicAdd(&fill[di], 1);
      csr_src[p] = si;
    }
  }
}

// ---------------------------------------------------------------------------
// k_gemm: round-14 exact. 468 blocks x 4 waves, one 16x16 C-tile per wave,
// LDS-free, barrier-free, 3 MFMA chains.
// ---------------------------------------------------------------------------
__global__ __launch_bounds__(256) void k_gemm(const unsigned short* __restrict__ xh,
                                              const unsigned short* __restrict__ xl,
                                              const unsigned short* __restrict__ Bh,
                                              const unsigned short* __restrict__ Bl,
                                              float* __restrict__ C) {
  int t = threadIdx.x;
  int wid = blockIdx.x * 4 + (t >> 6), lane = t & 63;
  int rt = wid / 52, ct = wid % 52;
  const s16x8* Ah = (const s16x8*)xh + (size_t)rt * 1536 + lane;
  const s16x8* Al = (const s16x8*)xl + (size_t)rt * 1536 + lane;
  const s16x8* Bhp = (const s16x8*)Bh + (size_t)ct * 1536 + lane;
  const s16x8* Blp = (const s16x8*)Bl + (size_t)ct * 1536 + lane;
  f32x4 a0 = {0.f, 0.f, 0.f, 0.f}, a1 = a0, a2 = a0;
#pragma unroll 6
  for (int kk = 0; kk < 24; ++kk) {
    s16x8 ah = Ah[kk * 64];
    s16x8 al = Al[kk * 64];
    s16x8 bh = Bhp[kk * 64];
    s16x8 bl = Blp[kk * 64];
    a0 = __builtin_amdgcn_mfma_f32_16x16x32_bf16(ah, bh, a0, 0, 0, 0);
    a1 = __builtin_amdgcn_mfma_f32_16x16x32_bf16(ah, bl, a1, 0, 0, 0);
    a2 = __builtin_amdgcn_mfma_f32_16x16x32_bf16(al, bh, a2, 0, 0, 0);
  }
  int row0 = rt * 16 + (lane >> 4) * 4, col = ct * 16 + (lane & 15);
#pragma unroll
  for (int r = 0; r < 4; ++r)
    C[(size_t)(row0 + r) * 832 + col] = a0[r] + a1[r] + a2[r];
}

// ---------------------------------------------------------------------------
// GAT aggregate (round-14 verified): 4-deep load batching, bit-identical
// accumulation order.
// ---------------------------------------------------------------------------
DEV float gat_aggregate(const float* __restrict__ C, const int* __restrict__ off,
                        const int* __restrict__ srcs, int n, int d, int h) {
  float aDv = C[(size_t)n * 832 + 772 + h];
  int e0 = off[n], e1 = off[n + 1];
  float num = 0.f, den = 0.f;
  for (int e = e0; e < e1; e += 4) {
    float lg[4], ms[4];
#pragma unroll
    for (int j = 0; j < 4; ++j) {
      int ee = (e + j < e1) ? (e + j) : e0;
      int s = srcs[ee];
      lg[j] = C[(size_t)s * 832 + 768 + h];
      ms[j] = C[(size_t)s * 832 + d];
    }
#pragma unroll
    for (int j = 0; j < 4; ++j) {
      if (e + j < e1) {
        float l = lg[j] + aDv;
        float lrel = l < 0.f ? 0.2f * l : l;
        lrel = fminf(fmaxf(lrel, -60.f), 40.f);
        float w = __expf(lrel);
        num += w * ms[j];
        den += w;
      }
    }
  }
  return num / den;
}

// k_gat (layers 0..3): writes ONLY xh/xl (xf dead for these layers).
__global__ __launch_bounds__(256) void k_gat(const float* __restrict__ C,
                                             const int* __restrict__ off,
                                             const int* __restrict__ srcs,
                                             const void* __restrict__ bG,
                                             const int* __restrict__ flg,
                                             int layer,
                                             unsigned short* __restrict__ xh,
                                             unsigned short* __restrict__ xl) {
  int fF = flg[0];
  int idx = blockIdx.x * 256 + threadIdx.x;  // 576*768
  int n = idx / 768, d = idx - n * 768, h = d / 192;
  float g = gelu_exact(gat_aggregate(C, off, srcs, n, d, h) +
                       ldf(bG, (size_t)layer * 768 + d, fF));
  unsigned short hi = f2b(g);
  size_t o = frag_off(n, d);
  xh[o] = hi;
  xl[o] = f2b(g - b2f((unsigned int)hi));
}

// k_gat_last (layer 4): only the 64 text-node rows, xf-only output.
// 49K threads (1 feature/thread) — TLP formulation; do NOT fuse into
// k_final (round-16: 64-wave serial tail, +90us).
__global__ __launch_bounds__(256) void k_gat_last(const float* __restrict__ C,
                                                  const int* __restrict__ off,
                                                  const int* __restrict__ srcs,
                                                  const void* __restrict__ bG,
                                                  const int* __restrict__ flg,
                                                  float* __restrict__ xf) {
  int fF = flg[0];
  int idx = blockIdx.x * 256 + threadIdx.x;  // 64*768
  int b = idx / 768, d = idx - b * 768, h = d / 192;
  int n = b * 9;  // text node of example b
  float g = gelu_exact(gat_aggregate(C, off, srcs, n, d, h) +
                       ldf(bG, (size_t)4 * 768 + d, fF));
  xf[(size_t)n * 768 + d] = g;
}

// ---------------------------------------------------------------------------
// k_final: round-9/14 exact (nt stores, 2 rows/wave, hoisted gathers).
// ---------------------------------------------------------------------------
DEV void final_row_f32(int r, int lane, const f32x4* wsrc,
                       const void* seg, const void* typ, const void* post,
                       const void* segt, const void* typt,
                       const void* gamma, const void* beta, int fI,
                       float* __restrict__ outp) {
  int s = r & 511;
  int sg = ldi(seg, (size_t)r, fI), tp = ldi(typ, (size_t)r, fI);
  const f32x4* pr = (const f32x4*)((const float*)post + (size_t)s * 768);
  const f32x4* sr = (const f32x4*)((const float*)segt + (size_t)sg * 768);
  const f32x4* tr = (const f32x4*)((const float*)typt + (size_t)tp * 768);
  float sum = 0.f, sq = 0.f;
  f32x4 vv[3];
#pragma unroll
  for (int j = 0; j < 3; ++j) {
    int p = lane + 64 * j;
    f32x4 a = wsrc[j];
    a += pr[p]; a += sr[p]; a += tr[p];
    vv[j] = a;
#pragma unroll
    for (int c = 0; c < 4; ++c) { sum += a[c]; sq += a[c] * a[c]; }
  }
#pragma unroll
  for (int o = 32; o > 0; o >>= 1) { sum += __shfl_down(sum, o); sq += __shfl_down(sq, o); }
  sum = __shfl(sum, 0); sq = __shfl(sq, 0);
  float mu = sum * (1.f / 768.f);
  float var = fmaxf(sq * (1.f / 768.f) - mu * mu, 0.f);
  float rstd = rsqrtf(var + 1e-6f);
  const f32x4* gm = (const f32x4*)gamma;
  const f32x4* bt = (const f32x4*)beta;
  f32x4* orow = (f32x4*)(outp + (size_t)r * 768);
#pragma unroll
  for (int j = 0; j < 3; ++j) {
    int p = lane + 64 * j;
    f32x4 g4 = gm[p], b4 = bt[p], y;
#pragma unroll
    for (int c = 0; c < 4; ++c) y[c] = g4[c] * (vv[j][c] - mu) * rstd + b4[c];
    __builtin_nontemporal_store(y, &orow[p]);
  }
}

DEV void final_row_bf16(int r, int lane, const void* src, const void* seg,
                        const void* typ, const void* word, const void* post,
                        const void* segt, const void* typt, const void* gamma,
                        const void* beta, const float* xf, int fI,
                        unsigned short* __restrict__ outp) {
  int b = r >> 9, s = r & 511;
  int sg = ldi(seg, (size_t)r, fI), tp = ldi(typ, (size_t)r, fI);
  int wrow = ldi(src, (size_t)r, fI);
  bool cls = (s == 0);
  float sum = 0.f, sq = 0.f;
  float vs[12];
#pragma unroll
  for (int j = 0; j < 12; ++j) {
    int d = lane + 64 * j;
    float xv = cls ? xf[(size_t)b * 6912 + d] : ldf(word, (size_t)wrow * 768 + d, 0);
    xv += ldf(post, (size_t)s * 768 + d, 0);
    xv += ldf(segt, (size_t)sg * 768 + d, 0);
    xv += ldf(typt, (size_t)tp * 768 + d, 0);
    vs[j] = xv;
    sum += xv; sq += xv * xv;
  }
#pragma unroll
  for (int o = 32; o > 0; o >>= 1) { sum += __shfl_down(sum, o); sq += __shfl_down(sq, o); }
  sum = __shfl(sum, 0); sq = __shfl(sq, 0);
  float mu = sum * (1.f / 768.f);
  float var = fmaxf(sq * (1.f / 768.f) - mu * mu, 0.f);
  float rstd = rsqrtf(var + 1e-6f);
#pragma unroll
  for (int j = 0; j < 12; ++j) {
    int d = lane + 64 * j;
    float y = ldf(gamma, (size_t)d, 0) * (vs[j] - mu) * rstd + ldf(beta, (size_t)d, 0);
    outp[(size_t)r * 768 + d] = f2b(y);
  }
}

__global__ __launch_bounds__(256) void k_final(const void* __restrict__ src,
                                               const void* __restrict__ seg,
                                               const void* __restrict__ typ,
                                               const void* __restrict__ word,
                                               const void* __restrict__ post,
                                               const void* __restrict__ segt,
                                               const void* __restrict__ typt,
                                               const void* __restrict__ gamma,
                                               const void* __restrict__ beta,
                                               const float* __restrict__ xf,
                                               const int* __restrict__ flg,
                                               void* __restrict__ out) {
  int fF = flg[0], fI = flg[1];
  int wave = threadIdx.x >> 6, lane = threadIdx.x & 63;
  int r0 = blockIdx.x * 4 + wave, r1 = r0 + 16384;
  if (fF) {
    int s0 = r0 & 511, s1 = r1 & 511;
    int b0 = r0 >> 9, b1 = r1 >> 9;
    int w0r = ldi(src, (size_t)r0, fI), w1r = ldi(src, (size_t)r1, fI);
    const f32x4* p0 = (s0 == 0) ? (const f32x4*)(xf + (size_t)b0 * 6912)
                                : (const f32x4*)((const float*)word + (size_t)w0r * 768);
    const f32x4* p1 = (s1 == 0) ? (const f32x4*)(xf + (size_t)b1 * 6912)
                                : (const f32x4*)((const float*)word + (size_t)w1r * 768);
    f32x4 wa[3], wb[3];
#pragma unroll
    for (int j = 0; j < 3; ++j) { wa[j] = p0[lane + 64 * j]; wb[j] = p1[lane + 64 * j]; }
    final_row_f32(r0, lane, wa, seg, typ, post, segt, typt, gamma, beta, fI, (float*)out);
    final_row_f32(r1, lane, wb, seg, typ, post, segt, typt, gamma, beta, fI, (float*)out);
  } else {
    final_row_bf16(r0, lane, src, seg, typ, word, post, segt, typt, gamma, beta, xf, fI,
                   (unsigned short*)out);
    final_row_bf16(r1, lane, src, seg, typ, word, post, segt, typt, gamma, beta, xf, fI,
                   (unsigned short*)out);
  }
}

extern "C" void kernel_launch(void* const* d_in, const int* in_sizes, int n_in,
                              void* d_out, int out_size, void* d_ws, size_t ws_size,
                              hipStream_t stream) {
  const void* src  = d_in[0];
  const void* seg  = d_in[1];
  const void* typ  = d_in[2];
  const void* pos  = d_in[3];
  const void* sst  = d_in[4];
  const void* sen  = d_in[5];
  const void* edge = d_in[6];
  const void* word = d_in[7];
  const void* post = d_in[8];
  const void* segt = d_in[9];
  const void* typt = d_in[10];
  const void* gamma = d_in[11];
  const void* beta  = d_in[12];
  const void* Wg    = d_in[13];
  const void* aS    = d_in[14];
  const void* aD    = d_in[15];
  const void* bG    = d_in[16];

  char* ws = (char*)d_ws;
  float* xf = (float*)(ws);                               //  1,769,472
  float* C  = (float*)(ws + 1769472);                     //  1,916,928
  unsigned short* xh = (unsigned short*)(ws + 3686400);   //    884,736 (frag-linear)
  unsigned short* xl = (unsigned short*)(ws + 4571136);   //    884,736
  unsigned short* Bh = (unsigned short*)(ws + 5455872);   //  6,389,760 (5 layers, frag-linear)
  unsigned short* Bl = (unsigned short*)(ws + 11845632);  //  6,389,760
  int* csr_off = (int*)(ws + 18358272);                   //      2,320 (pad)
  int* csr_src = (int*)(ws + 18360592);                   //     35,072
  int* flags   = (int*)(ws + 18395664);                   //          8

  k_front<<<dim3(1357), dim3(256), 0, stream>>>(src, sst, sen, edge, word, pos, aS, aD, Wg,
                                                xh, xl, Bh, Bl, csr_off, csr_src, flags);
  for (int l = 0; l < 4; ++l) {
    k_gemm<<<dim3(468), dim3(256), 0, stream>>>(xh, xl,
                                                Bh + (size_t)l * 832 * 768,
                                                Bl + (size_t)l * 832 * 768, C);
    k_gat<<<dim3(1728), dim3(256), 0, stream>>>(C, csr_off, csr_src, bG, flags, l, xh, xl);
  }
  k_gemm<<<dim3(468), dim3(256), 0, stream>>>(xh, xl,
                                              Bh + (size_t)4 * 832 * 768,
                                              Bl + (size_t)4 * 832 * 768, C);
  k_gat_last<<<dim3(192), dim3(256), 0, stream>>>(C, csr_off, csr_src, bG, flags, xf);
  k_final<<<dim3(4096), dim3(256), 0, stream>>>(src, seg, typ, word, post, segt, typt,
                                                gamma, beta, xf, flags, d_out);
}